// Round 1
// baseline (175.765 us; speedup 1.0000x reference)
//
#include <hip/hip_runtime.h>
#include <math.h>

#define NF 8
#define SS 5
#define DIN 64
#define KSTEP 3
#define BT 32
#define FH_PAD 68
#define FSTR (SS*FH_PAD)      // 340
#define HOPSTR (NF*FSTR)      // 2720
#define TAU 0.05f

// ws float layout: [0, 3*HOPSTR): fh padded [3][8][5][68]
//                  [3*HOPSTR, +120): sq_h [3][8][5]

__global__ __launch_bounds__(256) void hidden_prep(
    const float* __restrict__ adjs_hidden,
    const float* __restrict__ features_hidden,
    float* __restrict__ ws)
{
  __shared__ float Ah[NF][SS][SS];
  __shared__ float buf[2][NF][SS][DIN];
  const int t = threadIdx.x;

  if (t < NF*SS*SS) ((float*)Ah)[t] = 0.0f;
  for (int i = t; i < NF*SS*DIN; i += 256) ((float*)buf[0])[i] = features_hidden[i];
  __syncthreads();
  if (t < NF*10) {
    const int iu0[10] = {0,0,0,0,1,1,1,2,2,3};
    const int iu1[10] = {1,2,3,4,2,3,4,3,4,4};
    int f = t / 10, k = t % 10;
    float sg = 1.0f / (1.0f + expf(-adjs_hidden[t]));
    Ah[f][iu0[k]][iu1[k]] = sg;
    Ah[f][iu1[k]][iu0[k]] = sg;
  }
  __syncthreads();

  int cur = 0;
  for (int h = 0; h < KSTEP; ++h) {
    // write padded fh for this hop
    for (int i = t; i < NF*SS*DIN; i += 256) {
      int f = i / (SS*DIN), s = (i / DIN) % SS, d = i % DIN;
      ws[h*HOPSTR + f*FSTR + s*FH_PAD + d] = buf[cur][f][s][d];
    }
    // sq_h
    if (t < NF*SS) {
      float acc = 0.0f;
      int f = t / SS, s = t % SS;
      for (int d = 0; d < DIN; ++d) { float v = buf[cur][f][s][d]; acc = fmaf(v, v, acc); }
      ws[KSTEP*HOPSTR + h*NF*SS + t] = acc;
    }
    if (h + 1 < KSTEP) {
      __syncthreads();
      for (int i = t; i < NF*SS*DIN; i += 256) {
        int f = i / (SS*DIN), s = (i / DIN) % SS, d = i % DIN;
        float acc = 0.0f;
        for (int j = 0; j < SS; ++j) acc = fmaf(Ah[f][s][j], buf[cur][f][j][d], acc);
        buf[cur^1][f][s][d] = acc;
      }
      __syncthreads();
      cur ^= 1;
    }
  }
}

__global__ __launch_bounds__(256) void kc_main(
    const float* __restrict__ adjs,
    const float* __restrict__ feature,
    const int* __restrict__ idxs,
    const float* __restrict__ ws,
    float* __restrict__ out,
    int B, int N)
{
  __shared__ float fh[KSTEP*HOPSTR];        // 8160 f = 32640 B
  __shared__ float sqh[KSTEP][NF][SS];      // 480 B
  __shared__ float fS[BT][SS][FH_PAD];      // 43520 B
  __shared__ float adjS[BT][SS*SS];         // 3200 B
  __shared__ int   idxS[BT*SS];             // 640 B

  const int t = threadIdx.x;
  const int b0 = blockIdx.x * BT;

  for (int i = t; i < KSTEP*HOPSTR; i += 256) fh[i] = ws[i];
  for (int i = t; i < KSTEP*NF*SS; i += 256) ((float*)sqh)[i] = ws[KSTEP*HOPSTR + i];
  for (int i = t; i < BT*SS*SS; i += 256) {
    int b = i / (SS*SS);
    ((float*)adjS)[i] = (b0 + b < B) ? adjs[(size_t)b0*SS*SS + i] : 0.0f;
  }
  for (int i = t; i < BT*SS; i += 256) {
    int b = i / SS;
    idxS[i] = (b0 + b < B) ? idxs[(size_t)b0*SS + i] : -1;
  }
  __syncthreads();

  // gather feature rows: BT*SS rows x 16 float4
  for (int i = t; i < BT*SS*16; i += 256) {
    int row = i >> 4, d4 = i & 15;
    int id = idxS[row];
    float4 v = make_float4(0.f, 0.f, 0.f, 0.f);
    if ((unsigned)id < (unsigned)N)
      v = reinterpret_cast<const float4*>(feature)[(size_t)id*16 + d4];
    int b = row / SS, m = row % SS;
    *reinterpret_cast<float4*>(&fS[b][m][d4*4]) = v;
  }
  __syncthreads();

  const int b_i = t >> 3;   // 0..31
  const int f_  = t & 7;    // 0..7

  float total[SS][SS];
  #pragma unroll
  for (int m = 0; m < SS; ++m)
    #pragma unroll
    for (int s = 0; s < SS; ++s) total[m][s] = 0.0f;

  for (int hop = 0; hop < KSTEP; ++hop) {
    if (hop) {
      // f <- adjs @ f ; thread owns d-slice [f_*8, f_*8+8) of its b
      const int dbase = f_ * 8;
      float fo[SS][8];
      #pragma unroll
      for (int j = 0; j < SS; ++j)
        #pragma unroll
        for (int dd = 0; dd < 8; ++dd) fo[j][dd] = fS[b_i][j][dbase + dd];
      float fn[SS][8];
      #pragma unroll
      for (int m = 0; m < SS; ++m) {
        #pragma unroll
        for (int dd = 0; dd < 8; ++dd) fn[m][dd] = 0.0f;
        #pragma unroll
        for (int j = 0; j < SS; ++j) {
          float a = adjS[b_i][m*SS + j];
          #pragma unroll
          for (int dd = 0; dd < 8; ++dd) fn[m][dd] = fmaf(a, fo[j][dd], fn[m][dd]);
        }
      }
      __syncthreads();   // everyone done reading old f (cross phase of prev hop)
      #pragma unroll
      for (int m = 0; m < SS; ++m)
        #pragma unroll
        for (int dd = 0; dd < 8; ++dd) fS[b_i][m][dbase + dd] = fn[m][dd];
      __syncthreads();
    }

    float cr[SS][SS], sqf[SS];
    #pragma unroll
    for (int m = 0; m < SS; ++m) {
      sqf[m] = 0.0f;
      #pragma unroll
      for (int s = 0; s < SS; ++s) cr[m][s] = 0.0f;
    }

    const float* fhh = &fh[hop*HOPSTR + f_*FSTR];
    #pragma unroll
    for (int d4 = 0; d4 < 16; ++d4) {
      float4 fv[SS], hv[SS];
      #pragma unroll
      for (int m = 0; m < SS; ++m)
        fv[m] = *reinterpret_cast<const float4*>(&fS[b_i][m][d4*4]);
      #pragma unroll
      for (int s = 0; s < SS; ++s)
        hv[s] = *reinterpret_cast<const float4*>(&fhh[s*FH_PAD + d4*4]);
      #pragma unroll
      for (int m = 0; m < SS; ++m) {
        sqf[m] = fmaf(fv[m].x, fv[m].x, sqf[m]);
        sqf[m] = fmaf(fv[m].y, fv[m].y, sqf[m]);
        sqf[m] = fmaf(fv[m].z, fv[m].z, sqf[m]);
        sqf[m] = fmaf(fv[m].w, fv[m].w, sqf[m]);
        #pragma unroll
        for (int s = 0; s < SS; ++s) {
          cr[m][s] = fmaf(fv[m].x, hv[s].x, cr[m][s]);
          cr[m][s] = fmaf(fv[m].y, hv[s].y, cr[m][s]);
          cr[m][s] = fmaf(fv[m].z, hv[s].z, cr[m][s]);
          cr[m][s] = fmaf(fv[m].w, hv[s].w, cr[m][s]);
        }
      }
    }
    #pragma unroll
    for (int m = 0; m < SS; ++m)
      #pragma unroll
      for (int s = 0; s < SS; ++s) {
        float dist = sqf[m] + sqh[hop][f_][s] - 2.0f*cr[m][s];
        total[m][s] += expf(-(dist / 64.0f) / TAU);
      }
  }

  // greedy matching: row 0 -> col 0; rows 1..4 argmax over untaken cols
  float res = total[0][0];
  int taken = 1;
  #pragma unroll
  for (int r = 1; r < SS; ++r) {
    float best = -2.0f; int bi = 0;
    #pragma unroll
    for (int s = 0; s < SS; ++s) {
      float sc = ((taken >> s) & 1) ? -1.0f : total[r][s];
      if (sc > best) { best = sc; bi = s; }
    }
    res += best;
    taken |= (1 << bi);
  }
  const int bg = b0 + b_i;
  if (bg < B) out[(size_t)bg*NF + f_] = res;
}

extern "C" void kernel_launch(void* const* d_in, const int* in_sizes, int n_in,
                              void* d_out, int out_size, void* d_ws, size_t ws_size,
                              hipStream_t stream) {
  const float* adjs            = (const float*)d_in[0];
  const float* feature         = (const float*)d_in[1];
  const int*   idxs            = (const int*)d_in[2];
  const float* adjs_hidden     = (const float*)d_in[3];
  const float* features_hidden = (const float*)d_in[4];
  float* out = (float*)d_out;
  float* ws  = (float*)d_ws;

  const int B = in_sizes[0] / (SS*SS);
  const int N = in_sizes[1] / DIN;

  hipLaunchKernelGGL(hidden_prep, dim3(1), dim3(256), 0, stream,
                     adjs_hidden, features_hidden, ws);
  const int nblk = (B + BT - 1) / BT;
  hipLaunchKernelGGL(kc_main, dim3(nblk), dim3(256), 0, stream,
                     adjs, feature, idxs, ws, out, B, N);
}

// Round 2
// 151.104 us; speedup vs baseline: 1.1632x; 1.1632x over previous
//
#include <hip/hip_runtime.h>
#include <math.h>

#define NF 8
#define SS 5
#define DIN 64
#define KSTEP 3
#define BT 32
#define FH_PAD 68
#define FSTR (SS*FH_PAD)      // 340
#define HOPSTR (NF*FSTR)      // 2720

// log2(e)/3.2 and 2*log2(e)/3.2 : exp(-(sqf+sqh-2cr)/3.2) = 2^(CC*cr - CS*sqf - CS*sqh)
#define CS 0.45084219902780109f
#define CC 0.90168439805560218f

__device__ __forceinline__ float fexp2(float x) {
#if __has_builtin(__builtin_amdgcn_exp2f)
  return __builtin_amdgcn_exp2f(x);
#else
  return exp2f(x);
#endif
}

// ws float layout: [0, 3*HOPSTR): fh padded [3][8][5][68]
//                  [3*HOPSTR, +120): nsqh2 [3][8][5]  ( = -||fh||^2 * CS )

__global__ __launch_bounds__(256) void hidden_prep(
    const float* __restrict__ adjs_hidden,
    const float* __restrict__ features_hidden,
    float* __restrict__ ws)
{
  __shared__ float Ah[NF][SS][SS];
  __shared__ float buf[2][NF][SS][DIN];
  const int t = threadIdx.x;

  if (t < NF*SS*SS) ((float*)Ah)[t] = 0.0f;
  for (int i = t; i < NF*SS*DIN; i += 256) ((float*)buf[0])[i] = features_hidden[i];
  __syncthreads();
  if (t < NF*10) {
    const int iu0[10] = {0,0,0,0,1,1,1,2,2,3};
    const int iu1[10] = {1,2,3,4,2,3,4,3,4,4};
    int f = t / 10, k = t % 10;
    float sg = 1.0f / (1.0f + expf(-adjs_hidden[t]));
    Ah[f][iu0[k]][iu1[k]] = sg;
    Ah[f][iu1[k]][iu0[k]] = sg;
  }
  __syncthreads();

  int cur = 0;
  for (int h = 0; h < KSTEP; ++h) {
    // write padded fh for this hop
    for (int i = t; i < NF*SS*DIN; i += 256) {
      int f = i / (SS*DIN), s = (i / DIN) % SS, d = i % DIN;
      ws[h*HOPSTR + f*FSTR + s*FH_PAD + d] = buf[cur][f][s][d];
    }
    // negated, pre-scaled sq_h
    if (t < NF*SS) {
      float acc = 0.0f;
      int f = t / SS, s = t % SS;
      for (int d = 0; d < DIN; ++d) { float v = buf[cur][f][s][d]; acc = fmaf(v, v, acc); }
      ws[KSTEP*HOPSTR + h*NF*SS + t] = -acc * CS;
    }
    if (h + 1 < KSTEP) {
      __syncthreads();
      for (int i = t; i < NF*SS*DIN; i += 256) {
        int f = i / (SS*DIN), s = (i / DIN) % SS, d = i % DIN;
        float acc = 0.0f;
        for (int j = 0; j < SS; ++j) acc = fmaf(Ah[f][s][j], buf[cur][f][j][d], acc);
        buf[cur^1][f][s][d] = acc;
      }
      __syncthreads();
      cur ^= 1;
    }
  }
}

__global__ __launch_bounds__(256, 2) void kc_main(
    const float* __restrict__ adjs,
    const float* __restrict__ feature,
    const int* __restrict__ idxs,
    const float* __restrict__ ws,
    float* __restrict__ out,
    int B, int N)
{
  __shared__ float fh[KSTEP*HOPSTR];        // 32640 B
  __shared__ float nsqh[KSTEP][NF][SS];     // 480 B   (pre-negated, pre-scaled)
  __shared__ float fS[BT][SS][FH_PAD];      // 43520 B
  __shared__ float adjS[BT][SS*SS];         // 3200 B
  __shared__ float sqfS[BT][SS];            // 640 B   (pre-scaled by CS)
  __shared__ int   idxS[BT*SS];             // 640 B

  const int t = threadIdx.x;
  const int b0 = blockIdx.x * BT;

  for (int i = t; i < KSTEP*HOPSTR; i += 256) fh[i] = ws[i];
  for (int i = t; i < KSTEP*NF*SS; i += 256) ((float*)nsqh)[i] = ws[KSTEP*HOPSTR + i];
  for (int i = t; i < BT*SS*SS; i += 256) {
    int b = i / (SS*SS);
    ((float*)adjS)[i] = (b0 + b < B) ? adjs[(size_t)b0*SS*SS + i] : 0.0f;
  }
  for (int i = t; i < BT*SS; i += 256) {
    int b = i / SS;
    idxS[i] = (b0 + b < B) ? idxs[(size_t)b0*SS + i] : -1;
  }
  __syncthreads();

  // gather feature rows: BT*SS rows x 16 float4
  for (int i = t; i < BT*SS*16; i += 256) {
    int row = i >> 4, d4 = i & 15;
    int id = idxS[row];
    float4 v = make_float4(0.f, 0.f, 0.f, 0.f);
    if ((unsigned)id < (unsigned)N)
      v = reinterpret_cast<const float4*>(feature)[(size_t)id*16 + d4];
    int b = row / SS, m = row % SS;
    *reinterpret_cast<float4*>(&fS[b][m][d4*4]) = v;
  }
  __syncthreads();

  const int b_i = t >> 3;   // 0..31
  const int f_  = t & 7;    // 0..7

  float total[SS][SS];
  #pragma unroll
  for (int m = 0; m < SS; ++m)
    #pragma unroll
    for (int s = 0; s < SS; ++s) total[m][s] = 0.0f;

  for (int hop = 0; hop < KSTEP; ++hop) {
    if (hop) {
      // f <- adjs @ f ; thread owns d-slice [f_*8, f_*8+8) of its b
      const int dbase = f_ * 8;
      float fo[SS][8];
      #pragma unroll
      for (int j = 0; j < SS; ++j)
        #pragma unroll
        for (int dd = 0; dd < 8; ++dd) fo[j][dd] = fS[b_i][j][dbase + dd];
      float fn[SS][8];
      #pragma unroll
      for (int m = 0; m < SS; ++m) {
        #pragma unroll
        for (int dd = 0; dd < 8; ++dd) fn[m][dd] = 0.0f;
        #pragma unroll
        for (int j = 0; j < SS; ++j) {
          float a = adjS[b_i][m*SS + j];
          #pragma unroll
          for (int dd = 0; dd < 8; ++dd) fn[m][dd] = fmaf(a, fo[j][dd], fn[m][dd]);
        }
      }
      __syncthreads();   // everyone done reading old f
      #pragma unroll
      for (int m = 0; m < SS; ++m)
        #pragma unroll
        for (int dd = 0; dd < 8; ++dd) fS[b_i][m][dbase + dd] = fn[m][dd];
      __syncthreads();
    }

    // shared ||f||^2: lanes f_<5 each do one row of their b (pre-scaled by CS)
    if (f_ < SS) {
      float acc = 0.0f;
      const float* fr = &fS[b_i][f_][0];
      #pragma unroll
      for (int d4 = 0; d4 < 16; ++d4) {
        float4 v = *reinterpret_cast<const float4*>(&fr[d4*4]);
        acc = fmaf(v.x, v.x, acc);
        acc = fmaf(v.y, v.y, acc);
        acc = fmaf(v.z, v.z, acc);
        acc = fmaf(v.w, v.w, acc);
      }
      sqfS[b_i][f_] = acc * CS;
    }
    __syncthreads();

    float cr[SS][SS];
    #pragma unroll
    for (int m = 0; m < SS; ++m)
      #pragma unroll
      for (int s = 0; s < SS; ++s) cr[m][s] = 0.0f;

    const float* fhh = &fh[hop*HOPSTR + f_*FSTR];
    #pragma unroll
    for (int d4 = 0; d4 < 16; ++d4) {
      float4 fv[SS], hv[SS];
      #pragma unroll
      for (int m = 0; m < SS; ++m)
        fv[m] = *reinterpret_cast<const float4*>(&fS[b_i][m][d4*4]);
      #pragma unroll
      for (int s = 0; s < SS; ++s)
        hv[s] = *reinterpret_cast<const float4*>(&fhh[s*FH_PAD + d4*4]);
      #pragma unroll
      for (int m = 0; m < SS; ++m)
        #pragma unroll
        for (int s = 0; s < SS; ++s) {
          cr[m][s] = fmaf(fv[m].x, hv[s].x, cr[m][s]);
          cr[m][s] = fmaf(fv[m].y, hv[s].y, cr[m][s]);
          cr[m][s] = fmaf(fv[m].z, hv[s].z, cr[m][s]);
          cr[m][s] = fmaf(fv[m].w, hv[s].w, cr[m][s]);
        }
    }

    float sqf2[SS], nh[SS];
    #pragma unroll
    for (int m = 0; m < SS; ++m) sqf2[m] = sqfS[b_i][m];
    #pragma unroll
    for (int s = 0; s < SS; ++s) nh[s] = nsqh[hop][f_][s];
    #pragma unroll
    for (int m = 0; m < SS; ++m)
      #pragma unroll
      for (int s = 0; s < SS; ++s) {
        float arg = fmaf(CC, cr[m][s], nh[s] - sqf2[m]);  // <= 0 always
        total[m][s] += fexp2(arg);
      }
  }

  // greedy matching: row 0 -> col 0; rows 1..4 argmax over untaken cols
  float res = total[0][0];
  int taken = 1;
  #pragma unroll
  for (int r = 1; r < SS; ++r) {
    float best = -2.0f; int bi = 0;
    #pragma unroll
    for (int s = 0; s < SS; ++s) {
      float sc = ((taken >> s) & 1) ? -1.0f : total[r][s];
      if (sc > best) { best = sc; bi = s; }
    }
    res += best;
    taken |= (1 << bi);
  }
  const int bg = b0 + b_i;
  if (bg < B) out[(size_t)bg*NF + f_] = res;
}

extern "C" void kernel_launch(void* const* d_in, const int* in_sizes, int n_in,
                              void* d_out, int out_size, void* d_ws, size_t ws_size,
                              hipStream_t stream) {
  const float* adjs            = (const float*)d_in[0];
  const float* feature         = (const float*)d_in[1];
  const int*   idxs            = (const int*)d_in[2];
  const float* adjs_hidden     = (const float*)d_in[3];
  const float* features_hidden = (const float*)d_in[4];
  float* out = (float*)d_out;
  float* ws  = (float*)d_ws;

  const int B = in_sizes[0] / (SS*SS);
  const int N = in_sizes[1] / DIN;

  hipLaunchKernelGGL(hidden_prep, dim3(1), dim3(256), 0, stream,
                     adjs_hidden, features_hidden, ws);
  const int nblk = (B + BT - 1) / BT;
  hipLaunchKernelGGL(kc_main, dim3(nblk), dim3(256), 0, stream,
                     adjs, feature, idxs, ws, out, B, N);
}